// Round 4
// baseline (318.275 us; speedup 1.0000x reference)
//
#include <hip/hip_runtime.h>

typedef unsigned short u16;
typedef __bf16 bf16x8 __attribute__((ext_vector_type(8)));
typedef float f32x4 __attribute__((ext_vector_type(4)));

union B8 { uint4 u; bf16x8 v; };
union U8 { u16 s[8]; uint4 u; };

#define NQ 2048
#define NK 2048
#define ND 128
#define NTASK 512   // 16 batches x 32 q-tiles of 64 rows

template<int C>
__device__ __forceinline__ float dppf(float x) {
  int v = __builtin_bit_cast(int, x);
  int r = __builtin_amdgcn_update_dpp(v, v, C, 0xF, 0xF, true);
  return __builtin_bit_cast(float, r);
}
__device__ __forceinline__ float rowmax16(float x) {
  x = fmaxf(x, dppf<0xB1>(x));   // quad_perm xor1
  x = fmaxf(x, dppf<0x4E>(x));   // quad_perm xor2
  x = fmaxf(x, dppf<0x141>(x));  // row_half_mirror
  x = fmaxf(x, dppf<0x140>(x));  // row_mirror
  return x;
}
__device__ __forceinline__ float rowsum16(float x) {
  x += dppf<0xB1>(x);
  x += dppf<0x4E>(x);
  x += dppf<0x141>(x);
  x += dppf<0x140>(x);
  return x;
}

__device__ __forceinline__ bf16x8 cvt8(float4 a, float4 b) {
  bf16x8 r;
  r[0] = (__bf16)a.x; r[1] = (__bf16)a.y; r[2] = (__bf16)a.z; r[3] = (__bf16)a.w;
  r[4] = (__bf16)b.x; r[5] = (__bf16)b.y; r[6] = (__bf16)b.z; r[7] = (__bf16)b.w;
  return r;
}

// Flash attention fwd, fp32 I/O, bf16 MFMA.
// Persistent: 256 blocks x 1024 threads (16 waves = 4 q-waves x 4 kv-groups).
// Tasks = (b, 64-row q-tile), grabbed via global atomic counter (d_ws) ->
// near-perfect load balance despite vl ~ U(1,2048). Group g does tiles t=4i+g
// into private (m,l,O); 4-way in-LDS merge per task. Per-wave tile datapath
// (K XOR-swizzle, V d-major scatter, P granule-XOR) is the verified path.
// LDS: 4x16KB sK + 4x16KB sV + 16x2KB sP = 160KB (1 block/CU, 4 waves/SIMD).
__global__ __launch_bounds__(1024, 4)
void flash_fwd(const float* __restrict__ qg, const float* __restrict__ kg,
               const float* __restrict__ vg, const int* __restrict__ vlg,
               float* __restrict__ og, int* __restrict__ gctr)
{
  __shared__ __align__(16) u16 smem[81920];   // 160 KB exactly

  const int tid  = threadIdx.x;
  const int lane = tid & 63;
  const int wv   = tid >> 6;     // wave 0..15
  const int qw   = wv & 3;       // q-wave 0..3 (16 rows each)
  const int grp  = wv >> 2;      // kv-group 0..3
  const int n    = lane & 15;
  const int quad = lane >> 4;

  // K tile grp: 64r x 128d, (row,g8) at row*128+((g8^(row&15))<<3)
  u16* const sKg = smem + grp * 8192;
  // V tile grp, d-major: (d,kv) at d*64+(((kv>>3)^(d&7))<<3)+(kv&7)
  u16* const sVg = smem + 32768 + grp * 8192;
  // P per wave: (row,c) at row*64+((((c>>3)^(row&7))<<3))+(c&7)
  u16* const Pw  = smem + 65536 + wv * 1024;
  // task-id broadcast: aliases wave-0's P buffer. Safe: written only by tid 0
  // (wave 0 owns that P buffer; same-wave program order), read before barrier1.
  int* const sTk = (int*)(smem + 65536);
  // merge region: aliases sK/sV (dead between last barrier2 and next staging)
  float* const fb = (float*)smem;

  // Staging: group's 256 threads own row srow, col-quarter scq (32 cols)
  const int gtid = tid & 255;
  const int srow = gtid >> 2, scq = gtid & 3;

  const float* kb = nullptr;
  const float* vb = nullptr;
  bf16x8 kreg[4], vreg[4];

  auto kload = [&](int t) {
    const float* src = kb + (size_t)(t * 64 + srow) * ND + scq * 32;
    #pragma unroll
    for (int c = 0; c < 4; ++c)
      kreg[c] = cvt8(*(const float4*)(src + c * 8), *(const float4*)(src + c * 8 + 4));
  };
  auto kstore = [&]() {
    #pragma unroll
    for (int c = 0; c < 4; ++c) {
      B8 tt; tt.v = kreg[c];
      *(uint4*)(&sKg[srow * 128 + (((scq * 4 + c) ^ (srow & 15)) << 3)]) = tt.u;
    }
  };
  auto vload = [&](int t) {
    const float* src = vb + (size_t)(t * 64 + srow) * ND + scq * 32;
    #pragma unroll
    for (int c = 0; c < 4; ++c)
      vreg[c] = cvt8(*(const float4*)(src + c * 8), *(const float4*)(src + c * 8 + 4));
  };
  auto vstore = [&]() {    // transpose-scatter: kv = srow, d = scq*32+c*8+j (d&7 == j)
    #pragma unroll
    for (int c = 0; c < 4; ++c) {
      B8 x; x.v = vreg[c];
      U8 tt; tt.u = x.u;
      #pragma unroll
      for (int j = 0; j < 8; ++j) {
        int d = scq * 32 + c * 8 + j;
        sVg[d * 64 + (((srow >> 3) ^ j) << 3) + (srow & 7)] = tt.s[j];
      }
    }
  };

  constexpr float CEXP = 0.08838834764831845f * 1.44269504088896340f; // log2e/sqrt(128)

  for (;;) {
    if (tid == 0) *sTk = atomicAdd(gctr, 1);
    __syncthreads();                       // broadcast; also orders prev-task merge reads
    const int task = *sTk;
    if (task >= NTASK) break;              // uniform exit

    const int b  = task >> 5;              // consecutive tasks share b -> K/V L2 reuse
    const int qt = task & 31;
    const int vl = vlg[b];
    const int nt = (vl + 63) >> 6;
    const int NS = (nt + 3) >> 2;
    const int qrow0 = qt * 64 + qw * 16;

    kb = kg + (size_t)(b * NK) * ND;
    vb = vg + (size_t)(b * NK) * ND;

    // Q fragments (A-layout: A[m=lane&15][k=quad*8+j]), live whole task
    bf16x8 qf[4];
    #pragma unroll
    for (int c = 0; c < 4; ++c) {
      const float* qp = qg + (size_t)(b * NQ + qrow0 + n) * ND + c * 32 + quad * 8;
      qf[c] = cvt8(*(const float4*)qp, *(const float4*)(qp + 4));
    }

    f32x4 O[8];
    float mst[4], lst[4];
    #pragma unroll
    for (int f = 0; f < 8; ++f) O[f] = (f32x4){0.f, 0.f, 0.f, 0.f};
    #pragma unroll
    for (int r = 0; r < 4; ++r) { mst[r] = -__builtin_inff(); lst[r] = 0.f; }

    if (grp < nt) { kload(grp); vload(grp); kstore(); vstore(); }

    for (int i = 0; i < NS; ++i) {
      __syncthreads();                     // barrier1: super-iter i tiles visible
      const int t  = 4 * i + grp;
      const int tn = t + 4;
      if (tn < nt) { kload(tn); vload(tn); }   // global->regs, overlaps compute

      if (t < nt) {
        // ---- S = Q * K^T  (16 MFMAs, 16 b128 reads) ----
        f32x4 S[4];
        #pragma unroll
        for (int jn = 0; jn < 4; ++jn) S[jn] = (f32x4){0.f, 0.f, 0.f, 0.f};
        #pragma unroll
        for (int c = 0; c < 4; ++c)
          #pragma unroll
          for (int jn = 0; jn < 4; ++jn) {
            B8 bb;   // B-frag: K[col=jn*16+n][d=c*32+quad*8+j]
            bb.u = *(const uint4*)(&sKg[(jn * 16 + n) * 128 + (((c * 4 + quad) ^ n) << 3)]);
            S[jn] = __builtin_amdgcn_mfma_f32_16x16x32_bf16(qf[c], bb.v, S[jn], 0, 0, 0);
          }

        // ---- mask tail columns (kv >= vl) ----
        if (t * 64 + 64 > vl) {
          #pragma unroll
          for (int jn = 0; jn < 4; ++jn) {
            const bool msk = (t * 64 + jn * 16 + n) >= vl;
            #pragma unroll
            for (int r = 0; r < 4; ++r)
              S[jn][r] = msk ? -1e30f : S[jn][r];
          }
        }

        // ---- online softmax (4 independent row-chains) ----
        float al[4];
        #pragma unroll
        for (int r = 0; r < 4; ++r) {
          float mx = fmaxf(fmaxf(S[0][r], S[1][r]), fmaxf(S[2][r], S[3][r]));
          mx = rowmax16(mx);
          float mnew = fmaxf(mst[r], mx);
          float a = __builtin_exp2f((mst[r] - mnew) * CEXP);
          mst[r] = mnew;
          float ssum = 0.f;
          #pragma unroll
          for (int jn = 0; jn < 4; ++jn) {
            float p = __builtin_exp2f((S[jn][r] - mnew) * CEXP);
            S[jn][r] = p;
            ssum += p;
          }
          ssum = rowsum16(ssum);
          lst[r] = lst[r] * a + ssum;
          al[r] = a;
        }
        #pragma unroll
        for (int f = 0; f < 8; ++f) {
          O[f][0] *= al[0]; O[f][1] *= al[1]; O[f][2] *= al[2]; O[f][3] *= al[3];
        }

        // P (C-layout) -> per-wave LDS; same-wave DS order guarantees RAW
        #pragma unroll
        for (int jn = 0; jn < 4; ++jn)
          #pragma unroll
          for (int r = 0; r < 4; ++r) {
            int row = quad * 4 + r;
            __bf16 h = (__bf16)S[jn][r];
            Pw[row * 64 + (((jn * 2 + (n >> 3)) ^ (row & 7)) << 3) + (n & 7)]
                = __builtin_bit_cast(u16, h);
          }

        // ---- O += P * V  (16 MFMAs, 2+16 b128 reads) ----
        #pragma unroll
        for (int kc = 0; kc < 2; ++kc) {
          B8 ta;   // A-frag: P[m=n][k=kc*32+quad*8+j]
          ta.u = *(const uint4*)(&Pw[n * 64 + (((kc * 4 + quad) ^ (n & 7)) << 3)]);
          bf16x8 af = ta.v;
          #pragma unroll
          for (int f = 0; f < 8; ++f) {
            int d = f * 16 + n;                 // d&7 == n&7
            B8 bb;   // B-frag: V[k=kv][n=d] from d-major sV
            bb.u = *(const uint4*)(&sVg[d * 64 + (((kc * 4 + quad) ^ (n & 7)) << 3)]);
            O[f] = __builtin_amdgcn_mfma_f32_16x16x32_bf16(af, bb.v, O[f], 0, 0, 0);
          }
        }
      }

      __syncthreads();                     // barrier2: all waves done reading tiles
      if (tn < nt) { kstore(); vstore(); }
    }

    // ---- 4-way merge (groups 1..3 -> LDS, group 0 combines) + epilogue ----
    if (grp != 0) {
      float* po = fb + (size_t)((grp - 1) * 4 + qw) * 2048;
      #pragma unroll
      for (int f = 0; f < 8; ++f)
        #pragma unroll
        for (int r = 0; r < 4; ++r)
          po[(quad * 4 + r) * 128 + f * 16 + n] = O[f][r];
      if (n == 0) {
        float* ps = fb + 24576 + ((grp - 1) * 4 + qw) * 32;
        #pragma unroll
        for (int r = 0; r < 4; ++r) {
          ps[(quad * 4 + r) * 2]     = mst[r];
          ps[(quad * 4 + r) * 2 + 1] = lst[r];
        }
      }
    }
    __syncthreads();                       // partials visible to group 0
    if (grp == 0) {
      #pragma unroll
      for (int r = 0; r < 4; ++r) {
        const int row = quad * 4 + r;
        float mg[3], lg[3];
        #pragma unroll
        for (int gi = 0; gi < 3; ++gi) {
          const float* ps = fb + 24576 + (gi * 4 + qw) * 32;
          mg[gi] = ps[row * 2];
          lg[gi] = ps[row * 2 + 1];
        }
        float mt = fmaxf(fmaxf(mst[r], mg[0]), fmaxf(mg[1], mg[2]));
        const float a0 = __builtin_exp2f((mst[r] - mt) * CEXP);  // exp2(-inf)=0 for empties
        float ag[3];
        float lt = lst[r] * a0;
        #pragma unroll
        for (int gi = 0; gi < 3; ++gi) {
          ag[gi] = __builtin_exp2f((mg[gi] - mt) * CEXP);
          lt += lg[gi] * ag[gi];
        }
        const float rl = 1.0f / lt;
        float* op = og + (size_t)(b * NQ + qrow0 + row) * ND + n;
        #pragma unroll
        for (int f = 0; f < 8; ++f) {
          float val = O[f][r] * a0;
          #pragma unroll
          for (int gi = 0; gi < 3; ++gi)
            val += fb[(size_t)(gi * 4 + qw) * 2048 + row * 128 + f * 16 + n] * ag[gi];
          op[f * 16] = val * rl;
        }
      }
    }
    // next iteration's task-grab __syncthreads orders g0's fb reads vs restaging
  }
}

extern "C" void kernel_launch(void* const* d_in, const int* in_sizes, int n_in,
                              void* d_out, int out_size, void* d_ws, size_t ws_size,
                              hipStream_t stream) {
  const float* q  = (const float*)d_in[0];
  const float* k  = (const float*)d_in[1];
  const float* v  = (const float*)d_in[2];
  const int*  vl  = (const int*)d_in[3];
  float* out = (float*)d_out;

  hipMemsetAsync(d_ws, 0, 4, stream);   // reset task counter (async: capture-safe)
  hipLaunchKernelGGL(flash_fwd, dim3(256), dim3(1024), 0, stream,
                     q, k, v, vl, out, (int*)d_ws);
}

// Round 6
// 165.714 us; speedup vs baseline: 1.9206x; 1.9206x over previous
//
#include <hip/hip_runtime.h>

typedef unsigned short u16;
typedef __bf16 bf16x8 __attribute__((ext_vector_type(8)));
typedef float f32x4 __attribute__((ext_vector_type(4)));

union B8 { uint4 u; bf16x8 v; };
union U8 { u16 s[8]; uint4 u; };

#define NQ 2048
#define NK 2048
#define ND 128

template<int C>
__device__ __forceinline__ float dppf(float x) {
  int v = __builtin_bit_cast(int, x);
  int r = __builtin_amdgcn_update_dpp(v, v, C, 0xF, 0xF, true);
  return __builtin_bit_cast(float, r);
}
__device__ __forceinline__ float rowmax16(float x) {
  x = fmaxf(x, dppf<0xB1>(x));   // quad_perm xor1
  x = fmaxf(x, dppf<0x4E>(x));   // quad_perm xor2
  x = fmaxf(x, dppf<0x141>(x));  // row_half_mirror
  x = fmaxf(x, dppf<0x140>(x));  // row_mirror
  return x;
}
__device__ __forceinline__ float rowsum16(float x) {
  x += dppf<0xB1>(x);
  x += dppf<0x4E>(x);
  x += dppf<0x141>(x);
  x += dppf<0x140>(x);
  return x;
}

__device__ __forceinline__ bf16x8 cvt8(float4 a, float4 b) {
  bf16x8 r;
  r[0] = (__bf16)a.x; r[1] = (__bf16)a.y; r[2] = (__bf16)a.z; r[3] = (__bf16)a.w;
  r[4] = (__bf16)b.x; r[5] = (__bf16)b.y; r[6] = (__bf16)b.z; r[7] = (__bf16)b.w;
  return r;
}

// async 16B/lane global->LDS copy; LDS dest is wave-uniform base + lane*16.
__device__ __forceinline__ void async16(const u16* g, u16* l) {
  __builtin_amdgcn_global_load_lds(
      (const __attribute__((address_space(1))) unsigned int*)g,
      (__attribute__((address_space(3))) unsigned int*)l, 16, 0, 0);
}

// ---------- Prepass: fp32 K/V -> bf16 tile images in workspace ----------
// Image per (b, t) 64-row tile = exact byte image of the (verified) LDS layouts:
//   K: (row,g8) at row*128 + ((g8 ^ (row&15))<<3)             [8192 u16 = 16 KB]
//   V (d-major): (d,kv) at d*64 + (((kv>>3)^(d&7))<<3)+(kv&7) [8192 u16 = 16 KB]
__global__ __launch_bounds__(256)
void prepack(const float* __restrict__ kg, const float* __restrict__ vg,
             u16* __restrict__ wk, u16* __restrict__ wvp)
{
  __shared__ __align__(16) u16 sVp[8192];
  const int bt  = blockIdx.x;             // 0..511 = b*32 + t
  const int tid = threadIdx.x;
  const int srow = tid >> 2, scq = tid & 3;
  const size_t rowoff = (size_t)((bt >> 5) * NK + (bt & 31) * 64 + srow) * ND + scq * 32;

  // K: convert + swizzled vector store straight to the image
  u16* kimg = wk + (size_t)bt * 8192;
  {
    const float* src = kg + rowoff;
    #pragma unroll
    for (int c = 0; c < 4; ++c) {
      B8 tt; tt.v = cvt8(*(const float4*)(src + c * 8), *(const float4*)(src + c * 8 + 4));
      *(uint4*)(&kimg[srow * 128 + (((scq * 4 + c) ^ (srow & 15)) << 3)]) = tt.u;
    }
  }
  // V: convert + transpose-scatter into LDS image, then coalesced dump
  {
    const float* src = vg + rowoff;
    #pragma unroll
    for (int c = 0; c < 4; ++c) {
      B8 x; x.v = cvt8(*(const float4*)(src + c * 8), *(const float4*)(src + c * 8 + 4));
      U8 tt; tt.u = x.u;
      #pragma unroll
      for (int j = 0; j < 8; ++j) {
        int d = scq * 32 + c * 8 + j;
        sVp[d * 64 + (((srow >> 3) ^ j) << 3) + (srow & 7)] = tt.s[j];
      }
    }
  }
  __syncthreads();
  u16* vimg = wvp + (size_t)bt * 8192;
  const uint4* s4 = (const uint4*)sVp;
  uint4* d4 = (uint4*)vimg;
  #pragma unroll
  for (int k = 0; k < 4; ++k) d4[tid + 256 * k] = s4[tid + 256 * k];
}

// ---------- Main: flash attention fwd, bf16 MFMA, prestaged K/V images ----------
// 1024 threads = 16 waves = 8 q-waves (16 rows, Q-tile 128) x 2 kv-groups.
// Group g does tiles t=2i+g; double-buffered K/V staged via global_load_lds
// (images are LDS-linear) -> one barrier per super-iter, no cvt/ds_write staging.
// LDS: K 2g x 2buf x 16KB + V same + P 16 x 2KB = 160 KB exactly.
__global__ __launch_bounds__(1024)
void flash_fwd(const float* __restrict__ qg, const int* __restrict__ vlg,
               float* __restrict__ og,
               const u16* __restrict__ wk, const u16* __restrict__ wvp)
{
  __shared__ __align__(16) u16 smem[81920];   // 160 KB
  u16* const sKb = smem;            // [grp*2+buf][8192]
  u16* const sVb = smem + 32768;    // [grp*2+buf][8192]
  u16* const sPb = smem + 65536;    // [wave][1024]
  float* const fb = (float*)smem;   // merge scratch (post-loop)

  const int tid  = threadIdx.x;
  const int lane = tid & 63;
  const int wv   = tid >> 6;     // wave 0..15
  const int qw   = wv & 7;       // q-wave 0..7
  const int grp  = wv >> 3;      // kv-group 0/1
  const int n    = lane & 15;
  const int quad = lane >> 4;

  const int bi = blockIdx.x;
  // XCD-swizzle: XCD x (= bi&7) serves batches {2x, 2x+1}; 2MB bf16 K+V per XCD L2
  const int b  = ((bi & 7) << 1) | ((bi >> 3) & 1);
  const int qt = bi >> 4;

  const int vl = vlg[b];
  const int nt = (vl + 63) >> 6;

  const int qrow0 = qt * 128 + qw * 16;

  // Q fragments (A-layout: A[m=lane&15][k=quad*8+j]), live whole loop
  bf16x8 qf[4];
  #pragma unroll
  for (int c = 0; c < 4; ++c) {
    const float* qp = qg + (size_t)(b * NQ + qrow0 + n) * ND + c * 32 + quad * 8;
    qf[c] = cvt8(*(const float4*)qp, *(const float4*)(qp + 4));
  }

  f32x4 O[8];
  float mst[4], lst[4];
  #pragma unroll
  for (int f = 0; f < 8; ++f) O[f] = (f32x4){0.f, 0.f, 0.f, 0.f};
  #pragma unroll
  for (int r = 0; r < 4; ++r) { mst[r] = -__builtin_inff(); lst[r] = 0.f; }

  // Staging: group's 8 waves each async-copy a 2KB slice of the K and V images.
  #define STAGE(t, buf)                                                        \
    do {                                                                       \
      const size_t io_ = (size_t)(b * 32 + (t)) * 8192 + qw * 1024;            \
      const u16* gk_ = wk  + io_ + lane * 8;                                   \
      const u16* gv_ = wvp + io_ + lane * 8;                                   \
      u16* lk_ = sKb + (grp * 2 + (buf)) * 8192 + qw * 1024;                   \
      u16* lv_ = sVb + (grp * 2 + (buf)) * 8192 + qw * 1024;                   \
      async16(gk_,       lk_ + lane * 8);                                      \
      async16(gk_ + 512, lk_ + 512 + lane * 8);                                \
      async16(gv_,       lv_ + lane * 8);                                      \
      async16(gv_ + 512, lv_ + 512 + lane * 8);                                \
    } while (0)

  u16* const Pw = sPb + wv * 1024;

  constexpr float CEXP = 0.08838834764831845f * 1.44269504088896340f; // log2e/sqrt(128)

  if (grp < nt) STAGE(grp, 0);

  const int NS = (nt + 1) >> 1;
  for (int i = 0; i < NS; ++i) {
    __syncthreads();                 // vmcnt(0) drain before barrier => buf(i&1) ready
    const int t  = 2 * i + grp;
    const int tn = t + 2;
    if (tn < nt) STAGE(tn, (i + 1) & 1);   // fire-and-forget into other buffer

    if (t < nt) {
      const u16* Kg = sKb + (grp * 2 + (i & 1)) * 8192;
      const u16* Vg = sVb + (grp * 2 + (i & 1)) * 8192;

      // ---- S = Q * K^T  (16 MFMAs, 16 b128 reads) ----
      f32x4 S[4];
      #pragma unroll
      for (int jn = 0; jn < 4; ++jn) S[jn] = (f32x4){0.f, 0.f, 0.f, 0.f};
      #pragma unroll
      for (int c = 0; c < 4; ++c)
        #pragma unroll
        for (int jn = 0; jn < 4; ++jn) {
          B8 bb;   // B-frag: K[col=jn*16+n][d=c*32+quad*8+j]
          bb.u = *(const uint4*)(&Kg[(jn * 16 + n) * 128 + (((c * 4 + quad) ^ n) << 3)]);
          S[jn] = __builtin_amdgcn_mfma_f32_16x16x32_bf16(qf[c], bb.v, S[jn], 0, 0, 0);
        }

      // ---- mask tail columns (kv >= vl) ----
      if (t * 64 + 64 > vl) {
        #pragma unroll
        for (int jn = 0; jn < 4; ++jn) {
          const bool msk = (t * 64 + jn * 16 + n) >= vl;
          #pragma unroll
          for (int r = 0; r < 4; ++r)
            S[jn][r] = msk ? -1e30f : S[jn][r];
        }
      }

      // ---- online softmax (4 independent row-chains) ----
      float al[4];
      #pragma unroll
      for (int r = 0; r < 4; ++r) {
        float mx = fmaxf(fmaxf(S[0][r], S[1][r]), fmaxf(S[2][r], S[3][r]));
        mx = rowmax16(mx);
        float mnew = fmaxf(mst[r], mx);
        float a = __builtin_exp2f((mst[r] - mnew) * CEXP);
        mst[r] = mnew;
        float ssum = 0.f;
        #pragma unroll
        for (int jn = 0; jn < 4; ++jn) {
          float p = __builtin_exp2f((S[jn][r] - mnew) * CEXP);
          S[jn][r] = p;
          ssum += p;
        }
        ssum = rowsum16(ssum);
        lst[r] = lst[r] * a + ssum;
        al[r] = a;
      }
      #pragma unroll
      for (int f = 0; f < 8; ++f) {
        O[f][0] *= al[0]; O[f][1] *= al[1]; O[f][2] *= al[2]; O[f][3] *= al[3];
      }

      // P (C-layout) -> per-wave LDS; same-wave DS order guarantees RAW
      #pragma unroll
      for (int jn = 0; jn < 4; ++jn)
        #pragma unroll
        for (int r = 0; r < 4; ++r) {
          int row = quad * 4 + r;
          __bf16 h = (__bf16)S[jn][r];
          Pw[row * 64 + (((jn * 2 + (n >> 3)) ^ (row & 7)) << 3) + (n & 7)]
              = __builtin_bit_cast(u16, h);
        }

      // ---- O += P * V  (16 MFMAs, 2+16 b128 reads) ----
      #pragma unroll
      for (int kc = 0; kc < 2; ++kc) {
        B8 ta;   // A-frag: P[m=n][k=kc*32+quad*8+j]
        ta.u = *(const uint4*)(&Pw[n * 64 + (((kc * 4 + quad) ^ (n & 7)) << 3)]);
        bf16x8 af = ta.v;
        #pragma unroll
        for (int f = 0; f < 8; ++f) {
          int d = f * 16 + n;                 // d&7 == n&7
          B8 bb;   // B-frag: V[k=kv][n=d] from d-major sV
          bb.u = *(const uint4*)(&Vg[d * 64 + (((kc * 4 + quad) ^ (n & 7)) << 3)]);
          O[f] = __builtin_amdgcn_mfma_f32_16x16x32_bf16(af, bb.v, O[f], 0, 0, 0);
        }
      }
    }
  }

  // ---- cross-group merge (group 1 -> LDS, group 0 combines) + epilogue ----
  __syncthreads();                   // all compute/LDS reads done; smem reusable
  if (grp == 1) {
    float* po = fb + qw * 2048;      // 16 rows x 128 d
    #pragma unroll
    for (int f = 0; f < 8; ++f)
      #pragma unroll
      for (int r = 0; r < 4; ++r)
        po[(quad * 4 + r) * 128 + f * 16 + n] = O[f][r];
    if (n == 0) {
      float* ps = fb + 16384 + qw * 32;
      #pragma unroll
      for (int r = 0; r < 4; ++r) {
        ps[(quad * 4 + r) * 2]     = mst[r];
        ps[(quad * 4 + r) * 2 + 1] = lst[r];
      }
    }
  }
  __syncthreads();
  if (grp == 0) {
    const float* ps = fb + 16384 + qw * 32;
    #pragma unroll
    for (int r = 0; r < 4; ++r) {
      const int row = quad * 4 + r;
      const float m1 = ps[row * 2], l1 = ps[row * 2 + 1];
      const float m  = fmaxf(mst[r], m1);
      const float a0 = __builtin_exp2f((mst[r] - m) * CEXP);  // exp2(-inf)=0 for empties
      const float a1 = __builtin_exp2f((m1 - m) * CEXP);
      const float rl = 1.0f / (lst[r] * a0 + l1 * a1);
      float* op = og + (size_t)(b * NQ + qrow0 + row) * ND + n;
      #pragma unroll
      for (int f = 0; f < 8; ++f)
        op[f * 16] = (O[f][r] * a0 + fb[qw * 2048 + row * 128 + f * 16 + n] * a1) * rl;
    }
  }
}

// ---------- Fallback (workspace too small): round-3 kernel, reg staging ----------
__global__ __launch_bounds__(1024)
void flash_fwd_fb(const float* __restrict__ qg, const float* __restrict__ kg,
                  const float* __restrict__ vg, const int* __restrict__ vlg,
                  float* __restrict__ og)
{
  __shared__ __align__(16) u16 sK[2][64 * 128];
  __shared__ __align__(16) u16 sV[2][64 * 128];
  __shared__ __align__(16) u16 sP[16][16 * 64];

  const int tid  = threadIdx.x;
  const int lane = tid & 63;
  const int wv   = tid >> 6;
  const int qw   = wv & 7;
  const int grp  = wv >> 3;
  const int n    = lane & 15;
  const int quad = lane >> 4;

  const int bi = blockIdx.x;
  const int b  = ((bi & 7) << 1) | ((bi >> 3) & 1);
  const int qt = bi >> 4;

  const int vl = vlg[b];
  const int nt = (vl + 63) >> 6;
  const int qrow0 = qt * 128 + qw * 16;

  bf16x8 qf[4];
  #pragma unroll
  for (int c = 0; c < 4; ++c) {
    const float* qp = qg + (size_t)(b * NQ + qrow0 + n) * ND + c * 32 + quad * 8;
    qf[c] = cvt8(*(const float4*)qp, *(const float4*)(qp + 4));
  }

  f32x4 O[8];
  float mst[4], lst[4];
  #pragma unroll
  for (int f = 0; f < 8; ++f) O[f] = (f32x4){0.f, 0.f, 0.f, 0.f};
  #pragma unroll
  for (int r = 0; r < 4; ++r) { mst[r] = -__builtin_inff(); lst[r] = 0.f; }

  const float* kb = kg + (size_t)(b * NK) * ND;
  const float* vb = vg + (size_t)(b * NK) * ND;
  const int stid = tid & 511;
  const int srow = stid >> 3, sc8 = stid & 7;
  bf16x8 kreg[2], vreg[2];

  auto kload = [&](int t) {
    const float* src = kb + (size_t)(t * 64 + srow) * ND + sc8 * 16;
    #pragma unroll
    for (int c = 0; c < 2; ++c)
      kreg[c] = cvt8(*(const float4*)(src + c * 8), *(const float4*)(src + c * 8 + 4));
  };
  auto kstore = [&]() {
    #pragma unroll
    for (int c = 0; c < 2; ++c) {
      B8 tt; tt.v = kreg[c];
      *(uint4*)(&sK[grp][srow * 128 + (((sc8 * 2 + c) ^ (srow & 15)) << 3)]) = tt.u;
    }
  };
  auto vload = [&](int t) {
    const float* src = vb + (size_t)(t * 64 + srow) * ND + sc8 * 16;
    #pragma unroll
    for (int c = 0; c < 2; ++c)
      vreg[c] = cvt8(*(const float4*)(src + c * 8), *(const float4*)(src + c * 8 + 4));
  };
  auto vstore = [&]() {
    #pragma unroll
    for (int c = 0; c < 2; ++c) {
      B8 x; x.v = vreg[c];
      U8 tt; tt.u = x.u;
      #pragma unroll
      for (int j = 0; j < 8; ++j) {
        int d = sc8 * 16 + c * 8 + j;
        sV[grp][d * 64 + (((srow >> 3) ^ j) << 3) + (srow & 7)] = tt.s[j];
      }
    }
  };

  if (grp < nt) { kload(grp); vload(grp); kstore(); vstore(); }

  constexpr float CEXP = 0.08838834764831845f * 1.44269504088896340f;
  u16* Pw = sP[wv];
  const u16* Kg = sK[grp];
  const u16* Vg = sV[grp];

  const int NS = (nt + 1) >> 1;
  for (int i = 0; i < NS; ++i) {
    __syncthreads();
    const int t  = 2 * i + grp;
    const int tn = t + 2;
    if (tn < nt) { kload(tn); vload(tn); }

    if (t < nt) {
      f32x4 S[4];
      #pragma unroll
      for (int jn = 0; jn < 4; ++jn) S[jn] = (f32x4){0.f, 0.f, 0.f, 0.f};
      #pragma unroll
      for (int c = 0; c < 4; ++c)
        #pragma unroll
        for (int jn = 0; jn < 4; ++jn) {
          B8 bb;
          bb.u = *(const uint4*)(&Kg[(jn * 16 + n) * 128 + (((c * 4 + quad) ^ n) << 3)]);
          S[jn] = __builtin_amdgcn_mfma_f32_16x16x32_bf16(qf[c], bb.v, S[jn], 0, 0, 0);
        }
      if (t * 64 + 64 > vl) {
        #pragma unroll
        for (int jn = 0; jn < 4; ++jn) {
          const bool msk = (t * 64 + jn * 16 + n) >= vl;
          #pragma unroll
          for (int r = 0; r < 4; ++r)
            S[jn][r] = msk ? -1e30f : S[jn][r];
        }
      }
      float al[4];
      #pragma unroll
      for (int r = 0; r < 4; ++r) {
        float mx = fmaxf(fmaxf(S[0][r], S[1][r]), fmaxf(S[2][r], S[3][r]));
        mx = rowmax16(mx);
        float mnew = fmaxf(mst[r], mx);
        float a = __builtin_exp2f((mst[r] - mnew) * CEXP);
        mst[r] = mnew;
        float ssum = 0.f;
        #pragma unroll
        for (int jn = 0; jn < 4; ++jn) {
          float p = __builtin_exp2f((S[jn][r] - mnew) * CEXP);
          S[jn][r] = p;
          ssum += p;
        }
        ssum = rowsum16(ssum);
        lst[r] = lst[r] * a + ssum;
        al[r] = a;
      }
      #pragma unroll
      for (int f = 0; f < 8; ++f) {
        O[f][0] *= al[0]; O[f][1] *= al[1]; O[f][2] *= al[2]; O[f][3] *= al[3];
      }
      #pragma unroll
      for (int jn = 0; jn < 4; ++jn)
        #pragma unroll
        for (int r = 0; r < 4; ++r) {
          int row = quad * 4 + r;
          __bf16 h = (__bf16)S[jn][r];
          Pw[row * 64 + (((jn * 2 + (n >> 3)) ^ (row & 7)) << 3) + (n & 7)]
              = __builtin_bit_cast(u16, h);
        }
      #pragma unroll
      for (int kc = 0; kc < 2; ++kc) {
        B8 ta;
        ta.u = *(const uint4*)(&Pw[n * 64 + (((kc * 4 + quad) ^ (n & 7)) << 3)]);
        bf16x8 af = ta.v;
        #pragma unroll
        for (int f = 0; f < 8; ++f) {
          int d = f * 16 + n;
          B8 bb;
          bb.u = *(const uint4*)(&Vg[d * 64 + (((kc * 4 + quad) ^ (n & 7)) << 3)]);
          O[f] = __builtin_amdgcn_mfma_f32_16x16x32_bf16(af, bb.v, O[f], 0, 0, 0);
        }
      }
    }
    __syncthreads();
    if (tn < nt) { kstore(); vstore(); }
  }

  if (grp == 1) {
    float* ob = ((qw < 4) ? (float*)sK : (float*)sV) + (qw & 3) * 2048 + lane * 32;
    #pragma unroll
    for (int f = 0; f < 8; ++f)
      #pragma unroll
      for (int r = 0; r < 4; ++r)
        ob[f * 4 + r] = O[f][r];
    float* sb = (float*)sP + qw * 512 + lane * 8;
    #pragma unroll
    for (int r = 0; r < 4; ++r) { sb[r] = mst[r]; sb[4 + r] = lst[r]; }
  }
  __syncthreads();
  if (grp == 0) {
    const float* ob = ((qw < 4) ? (const float*)sK : (const float*)sV) + (qw & 3) * 2048 + lane * 32;
    const float* sb = (const float*)sP + qw * 512 + lane * 8;
    #pragma unroll
    for (int r = 0; r < 4; ++r) {
      const float m1 = sb[r], l1 = sb[4 + r];
      const float m  = fmaxf(mst[r], m1);
      const float a0 = __builtin_exp2f((mst[r] - m) * CEXP);
      const float a1 = __builtin_exp2f((m1 - m) * CEXP);
      const float rl = 1.0f / (lst[r] * a0 + l1 * a1);
      const int qrow = qrow0 + quad * 4 + r;
      float* op = og + (size_t)(b * NQ + qrow) * ND + n;
      #pragma unroll
      for (int f = 0; f < 8; ++f)
        op[f * 16] = (O[f][r] * a0 + ob[f * 4 + r] * a1) * rl;
    }
  }
}

extern "C" void kernel_launch(void* const* d_in, const int* in_sizes, int n_in,
                              void* d_out, int out_size, void* d_ws, size_t ws_size,
                              hipStream_t stream) {
  const float* q  = (const float*)d_in[0];
  const float* k  = (const float*)d_in[1];
  const float* v  = (const float*)d_in[2];
  const int*  vl  = (const int*)d_in[3];
  float* out = (float*)d_out;

  const size_t need = (size_t)16 * 1024 * 1024;   // K + V bf16 tile images
  if (ws_size >= need) {
    u16* wk  = (u16*)d_ws;
    u16* wvv = wk + 4194304;
    hipLaunchKernelGGL(prepack, dim3(512), dim3(256), 0, stream, k, v, wk, wvv);
    hipLaunchKernelGGL(flash_fwd, dim3(256), dim3(1024), 0, stream, q, vl, out, wk, wvv);
  } else {
    hipLaunchKernelGGL(flash_fwd_fb, dim3(256), dim3(1024), 0, stream, q, k, v, vl, out);
  }
}

// Round 7
// 162.595 us; speedup vs baseline: 1.9575x; 1.0192x over previous
//
#include <hip/hip_runtime.h>

typedef unsigned short u16;
typedef __bf16 bf16x8 __attribute__((ext_vector_type(8)));
typedef float f32x4 __attribute__((ext_vector_type(4)));

union B8 { uint4 u; bf16x8 v; };
union U8 { u16 s[8]; uint4 u; };

#define NQ 2048
#define NK 2048
#define ND 128

template<int C>
__device__ __forceinline__ float dppf(float x) {
  int v = __builtin_bit_cast(int, x);
  int r = __builtin_amdgcn_update_dpp(v, v, C, 0xF, 0xF, true);
  return __builtin_bit_cast(float, r);
}
__device__ __forceinline__ float rowmax16(float x) {
  x = fmaxf(x, dppf<0xB1>(x));   // quad_perm xor1
  x = fmaxf(x, dppf<0x4E>(x));   // quad_perm xor2
  x = fmaxf(x, dppf<0x141>(x));  // row_half_mirror
  x = fmaxf(x, dppf<0x140>(x));  // row_mirror
  return x;
}
__device__ __forceinline__ float rowsum16(float x) {
  x += dppf<0xB1>(x);
  x += dppf<0x4E>(x);
  x += dppf<0x141>(x);
  x += dppf<0x140>(x);
  return x;
}

__device__ __forceinline__ bf16x8 cvt8(float4 a, float4 b) {
  bf16x8 r;
  r[0] = (__bf16)a.x; r[1] = (__bf16)a.y; r[2] = (__bf16)a.z; r[3] = (__bf16)a.w;
  r[4] = (__bf16)b.x; r[5] = (__bf16)b.y; r[6] = (__bf16)b.z; r[7] = (__bf16)b.w;
  return r;
}

// async 16B/lane global->LDS copy; HW writes LDS at wave-uniform base + lane*16.
__device__ __forceinline__ void async16(const u16* g, u16* l) {
  __builtin_amdgcn_global_load_lds(
      (const __attribute__((address_space(1))) unsigned int*)g,
      (__attribute__((address_space(3))) unsigned int*)l, 16, 0, 0);
}

// ---------- Prepass: fp32 K/V -> bf16 tile images in workspace (verified r6) ----------
//   K: (row,g8) at row*128 + ((g8 ^ (row&15))<<3)             [8192 u16 = 16 KB]
//   V (d-major): (d,kv) at d*64 + (((kv>>3)^(d&7))<<3)+(kv&7) [8192 u16 = 16 KB]
__global__ __launch_bounds__(256)
void prepack(const float* __restrict__ kg, const float* __restrict__ vg,
             u16* __restrict__ wk, u16* __restrict__ wvp)
{
  __shared__ __align__(16) u16 sVp[8192];
  const int bt  = blockIdx.x;             // 0..511 = b*32 + t
  const int tid = threadIdx.x;
  const int srow = tid >> 2, scq = tid & 3;
  const size_t rowoff = (size_t)((bt >> 5) * NK + (bt & 31) * 64 + srow) * ND + scq * 32;

  u16* kimg = wk + (size_t)bt * 8192;
  {
    const float* src = kg + rowoff;
    #pragma unroll
    for (int c = 0; c < 4; ++c) {
      B8 tt; tt.v = cvt8(*(const float4*)(src + c * 8), *(const float4*)(src + c * 8 + 4));
      *(uint4*)(&kimg[srow * 128 + (((scq * 4 + c) ^ (srow & 15)) << 3)]) = tt.u;
    }
  }
  {
    const float* src = vg + rowoff;
    #pragma unroll
    for (int c = 0; c < 4; ++c) {
      B8 x; x.v = cvt8(*(const float4*)(src + c * 8), *(const float4*)(src + c * 8 + 4));
      U8 tt; tt.u = x.u;
      #pragma unroll
      for (int j = 0; j < 8; ++j) {
        int d = scq * 32 + c * 8 + j;
        sVp[d * 64 + (((srow >> 3) ^ j) << 3) + (srow & 7)] = tt.s[j];
      }
    }
  }
  __syncthreads();
  u16* vimg = wvp + (size_t)bt * 8192;
  const uint4* s4 = (const uint4*)sVp;
  uint4* d4 = (uint4*)vimg;
  #pragma unroll
  for (int k = 0; k < 4; ++k) d4[tid + 256 * k] = s4[tid + 256 * k];
}

// ---------- Main: 512 threads = 8 waves = 4 q-waves (32 rows, m2) x 2 kv-groups ----------
// Each wave owns 2 m-blocks sharing every K/V B-fragment (halves DS-port reads/row).
// Double-buffered K/V via global_load_lds from prepacked images; 1 barrier/super-iter.
// LDS: K 2g x 2buf x 16KB + V same + P 8 x 4KB = 160 KB. Epilogue merges in LDS,
// then coalesced float4 dump of the block's contiguous 64 KB output region.
__global__ __launch_bounds__(512, 2)
void flash_fwd(const float* __restrict__ qg, const int* __restrict__ vlg,
               float* __restrict__ og,
               const u16* __restrict__ wk, const u16* __restrict__ wvp)
{
  __shared__ __align__(16) u16 smem[81920];   // 160 KB
  u16* const sKb = smem;            // [grp*2+buf][8192]
  u16* const sVb = smem + 32768;    // [grp*2+buf][8192]
  u16* const sPb = smem + 65536;    // [wave][2048]
  float* const fb = (float*)smem;   // epilogue: 128x128 fp32 (64KB) + m/l at +16384

  const int tid  = threadIdx.x;
  const int lane = tid & 63;
  const int wv   = tid >> 6;     // wave 0..7
  const int qw   = wv & 3;       // q-wave 0..3 (32 rows each)
  const int grp  = wv >> 2;      // kv-group 0/1
  const int n    = lane & 15;
  const int quad = lane >> 4;

  const int bi = blockIdx.x;
  // XCD-swizzle: XCD x (= bi&7) serves batches {2x, 2x+1}; 2MB bf16 K+V per XCD L2
  const int b  = ((bi & 7) << 1) | ((bi >> 3) & 1);
  const int qt = bi >> 4;

  const int vl = vlg[b];
  const int nt = (vl + 63) >> 6;

  const int qrow0 = qt * 128 + qw * 32;

  // Q fragments (A-layout: A[m=lane&15][k=quad*8+j]), r2-verified mb indexing
  bf16x8 qf[2][4];
  #pragma unroll
  for (int mb = 0; mb < 2; ++mb)
    #pragma unroll
    for (int c = 0; c < 4; ++c) {
      const float* qp = qg + (size_t)(b * NQ + qrow0 + mb * 16 + n) * ND + c * 32 + quad * 8;
      qf[mb][c] = cvt8(*(const float4*)qp, *(const float4*)(qp + 4));
    }

  f32x4 O[2][8];
  float mst[2][4], lst[2][4];
  #pragma unroll
  for (int mb = 0; mb < 2; ++mb) {
    #pragma unroll
    for (int f = 0; f < 8; ++f) O[mb][f] = (f32x4){0.f, 0.f, 0.f, 0.f};
    #pragma unroll
    for (int r = 0; r < 4; ++r) { mst[mb][r] = -__builtin_inff(); lst[mb][r] = 0.f; }
  }

  // Staging: each group's 4 waves async-copy their 2048-u16 slice of K and V images.
  #define STAGE(t, buf)                                                        \
    do {                                                                       \
      const size_t io_ = (size_t)(b * 32 + (t)) * 8192 + qw * 2048;            \
      const u16* gk_ = wk  + io_ + lane * 8;                                   \
      const u16* gv_ = wvp + io_ + lane * 8;                                   \
      u16* lk_ = sKb + (grp * 2 + (buf)) * 8192 + qw * 2048;                   \
      u16* lv_ = sVb + (grp * 2 + (buf)) * 8192 + qw * 2048;                   \
      _Pragma("unroll")                                                        \
      for (int j_ = 0; j_ < 4; ++j_) {                                         \
        async16(gk_ + j_ * 512, lk_ + j_ * 512 + lane * 8);                    \
        async16(gv_ + j_ * 512, lv_ + j_ * 512 + lane * 8);                    \
      }                                                                        \
    } while (0)

  u16* const Pw = sPb + wv * 2048;

  constexpr float CEXP = 0.08838834764831845f * 1.44269504088896340f; // log2e/sqrt(128)

  if (grp < nt) STAGE(grp, 0);

  const int NS = (nt + 1) >> 1;
  for (int i = 0; i < NS; ++i) {
    __syncthreads();                 // vmcnt(0) drain before barrier => buf(i&1) ready
    const int t  = 2 * i + grp;
    const int tn = t + 2;
    if (tn < nt) STAGE(tn, (i + 1) & 1);   // fire-and-forget into other buffer

    if (t < nt) {
      const u16* Kg = sKb + (grp * 2 + (i & 1)) * 8192;
      const u16* Vg = sVb + (grp * 2 + (i & 1)) * 8192;

      // ---- S = Q*K^T (32 MFMAs, 16 b128 reads: B-frag reused across 2 m-blocks) ----
      f32x4 S[2][4];
      #pragma unroll
      for (int mb = 0; mb < 2; ++mb)
        #pragma unroll
        for (int jn = 0; jn < 4; ++jn) S[mb][jn] = (f32x4){0.f, 0.f, 0.f, 0.f};
      #pragma unroll
      for (int c = 0; c < 4; ++c)
        #pragma unroll
        for (int jn = 0; jn < 4; ++jn) {
          B8 bb;   // B-frag: K[col=jn*16+n][d=c*32+quad*8+j]
          bb.u = *(const uint4*)(&Kg[(jn * 16 + n) * 128 + (((c * 4 + quad) ^ n) << 3)]);
          S[0][jn] = __builtin_amdgcn_mfma_f32_16x16x32_bf16(qf[0][c], bb.v, S[0][jn], 0, 0, 0);
          S[1][jn] = __builtin_amdgcn_mfma_f32_16x16x32_bf16(qf[1][c], bb.v, S[1][jn], 0, 0, 0);
        }

      // ---- mask tail columns (kv >= vl) ----
      if (t * 64 + 64 > vl) {
        #pragma unroll
        for (int jn = 0; jn < 4; ++jn) {
          const bool msk = (t * 64 + jn * 16 + n) >= vl;
          #pragma unroll
          for (int r = 0; r < 4; ++r) {
            S[0][jn][r] = msk ? -1e30f : S[0][jn][r];
            S[1][jn][r] = msk ? -1e30f : S[1][jn][r];
          }
        }
      }

      // ---- online softmax (8 independent row-chains) ----
      float al[2][4];
      #pragma unroll
      for (int mb = 0; mb < 2; ++mb)
        #pragma unroll
        for (int r = 0; r < 4; ++r) {
          float mx = fmaxf(fmaxf(S[mb][0][r], S[mb][1][r]), fmaxf(S[mb][2][r], S[mb][3][r]));
          mx = rowmax16(mx);
          float mnew = fmaxf(mst[mb][r], mx);
          float a = __builtin_exp2f((mst[mb][r] - mnew) * CEXP);
          mst[mb][r] = mnew;
          float ssum = 0.f;
          #pragma unroll
          for (int jn = 0; jn < 4; ++jn) {
            float p = __builtin_exp2f((S[mb][jn][r] - mnew) * CEXP);
            S[mb][jn][r] = p;
            ssum += p;
          }
          ssum = rowsum16(ssum);
          lst[mb][r] = lst[mb][r] * a + ssum;
          al[mb][r] = a;
        }
      #pragma unroll
      for (int mb = 0; mb < 2; ++mb)
        #pragma unroll
        for (int f = 0; f < 8; ++f) {
          O[mb][f][0] *= al[mb][0]; O[mb][f][1] *= al[mb][1];
          O[mb][f][2] *= al[mb][2]; O[mb][f][3] *= al[mb][3];
        }

      // P (C-layout) -> per-wave LDS (r2-verified); same-wave DS order gives RAW
      #pragma unroll
      for (int mb = 0; mb < 2; ++mb)
        #pragma unroll
        for (int jn = 0; jn < 4; ++jn)
          #pragma unroll
          for (int r = 0; r < 4; ++r) {
            int row = mb * 16 + quad * 4 + r;
            __bf16 h = (__bf16)S[mb][jn][r];
            Pw[row * 64 + (((jn * 2 + (n >> 3)) ^ (row & 7)) << 3) + (n & 7)]
                = __builtin_bit_cast(u16, h);
          }

      // ---- O += P*V (32 MFMAs; V B-frag read once, reused across 2 m-blocks) ----
      #pragma unroll
      for (int kc = 0; kc < 2; ++kc) {
        bf16x8 af[2];
        #pragma unroll
        for (int mb = 0; mb < 2; ++mb) {
          B8 ta;   // A-frag: P[m=mb*16+n][k=kc*32+quad*8+j]
          ta.u = *(const uint4*)(&Pw[(mb * 16 + n) * 64 + (((kc * 4 + quad) ^ (n & 7)) << 3)]);
          af[mb] = ta.v;
        }
        #pragma unroll
        for (int f = 0; f < 8; ++f) {
          int d = f * 16 + n;                 // d&7 == n&7
          B8 bb;   // B-frag: V[k=kv][n=d] from d-major sV
          bb.u = *(const uint4*)(&Vg[d * 64 + (((kc * 4 + quad) ^ (n & 7)) << 3)]);
          O[0][f] = __builtin_amdgcn_mfma_f32_16x16x32_bf16(af[0], bb.v, O[0][f], 0, 0, 0);
          O[1][f] = __builtin_amdgcn_mfma_f32_16x16x32_bf16(af[1], bb.v, O[1][f], 0, 0, 0);
        }
      }
    }
  }
  #undef STAGE

  // ---- epilogue: merge in LDS fp32 buffer, then coalesced float4 dump ----
  __syncthreads();                   // all loop LDS reads done; smem reusable
  float* const ps = fb + 16384;      // m/l: [row]*2 (256 floats)
  if (grp == 1) {
    #pragma unroll
    for (int mb = 0; mb < 2; ++mb) {
      #pragma unroll
      for (int f = 0; f < 8; ++f)
        #pragma unroll
        for (int r = 0; r < 4; ++r)
          fb[(qw * 32 + mb * 16 + quad * 4 + r) * 128 + f * 16 + n] = O[mb][f][r];
      if (n == 0) {
        #pragma unroll
        for (int r = 0; r < 4; ++r) {
          const int row = qw * 32 + mb * 16 + quad * 4 + r;
          ps[row * 2]     = mst[mb][r];
          ps[row * 2 + 1] = lst[mb][r];
        }
      }
    }
  }
  __syncthreads();                   // grp1 partials visible
  if (grp == 0) {
    #pragma unroll
    for (int mb = 0; mb < 2; ++mb)
      #pragma unroll
      for (int r = 0; r < 4; ++r) {
        const int row = qw * 32 + mb * 16 + quad * 4 + r;
        const float m1 = ps[row * 2], l1 = ps[row * 2 + 1];
        const float m  = fmaxf(mst[mb][r], m1);
        const float a0 = __builtin_exp2f((mst[mb][r] - m) * CEXP);  // exp2(-inf)=0
        const float a1 = __builtin_exp2f((m1 - m) * CEXP);
        const float rl = 1.0f / (lst[mb][r] * a0 + l1 * a1);
        #pragma unroll
        for (int f = 0; f < 8; ++f) {
          const int idx = row * 128 + f * 16 + n;
          fb[idx] = (O[mb][f][r] * a0 + fb[idx] * a1) * rl;   // same-thread RMW
        }
      }
  }
  __syncthreads();                   // merged tile ready
  {
    // block's output = contiguous 16384 floats at (b, qt*128, 0)
    const float4* s4 = (const float4*)fb;
    float4* d4 = (float4*)(og + (size_t)(b * NQ + qt * 128) * ND);
    #pragma unroll
    for (int k = 0; k < 8; ++k)
      d4[tid + 512 * k] = s4[tid + 512 * k];
  }
}

// ---------- Fallback (workspace too small): r6 fallback, verified ----------
__global__ __launch_bounds__(1024)
void flash_fwd_fb(const float* __restrict__ qg, const float* __restrict__ kg,
                  const float* __restrict__ vg, const int* __restrict__ vlg,
                  float* __restrict__ og)
{
  __shared__ __align__(16) u16 sK[2][64 * 128];
  __shared__ __align__(16) u16 sV[2][64 * 128];
  __shared__ __align__(16) u16 sP[16][16 * 64];

  const int tid  = threadIdx.x;
  const int lane = tid & 63;
  const int wv   = tid >> 6;
  const int qw   = wv & 7;
  const int grp  = wv >> 3;
  const int n    = lane & 15;
  const int quad = lane >> 4;

  const int bi = blockIdx.x;
  const int b  = ((bi & 7) << 1) | ((bi >> 3) & 1);
  const int qt = bi >> 4;

  const int vl = vlg[b];
  const int nt = (vl + 63) >> 6;
  const int qrow0 = qt * 128 + qw * 16;

  bf16x8 qf[4];
  #pragma unroll
  for (int c = 0; c < 4; ++c) {
    const float* qp = qg + (size_t)(b * NQ + qrow0 + n) * ND + c * 32 + quad * 8;
    qf[c] = cvt8(*(const float4*)qp, *(const float4*)(qp + 4));
  }

  f32x4 O[8];
  float mst[4], lst[4];
  #pragma unroll
  for (int f = 0; f < 8; ++f) O[f] = (f32x4){0.f, 0.f, 0.f, 0.f};
  #pragma unroll
  for (int r = 0; r < 4; ++r) { mst[r] = -__builtin_inff(); lst[r] = 0.f; }

  const float* kb = kg + (size_t)(b * NK) * ND;
  const float* vb = vg + (size_t)(b * NK) * ND;
  const int stid = tid & 511;
  const int srow = stid >> 3, sc8 = stid & 7;
  bf16x8 kreg[2], vreg[2];

  auto kload = [&](int t) {
    const float* src = kb + (size_t)(t * 64 + srow) * ND + sc8 * 16;
    #pragma unroll
    for (int c = 0; c < 2; ++c)
      kreg[c] = cvt8(*(const float4*)(src + c * 8), *(const float4*)(src + c * 8 + 4));
  };
  auto kstore = [&]() {
    #pragma unroll
    for (int c = 0; c < 2; ++c) {
      B8 tt; tt.v = kreg[c];
      *(uint4*)(&sK[grp][srow * 128 + (((sc8 * 2 + c) ^ (srow & 15)) << 3)]) = tt.u;
    }
  };
  auto vload = [&](int t) {
    const float* src = vb + (size_t)(t * 64 + srow) * ND + sc8 * 16;
    #pragma unroll
    for (int c = 0; c < 2; ++c)
      vreg[c] = cvt8(*(const float4*)(src + c * 8), *(const float4*)(src + c * 8 + 4));
  };
  auto vstore = [&]() {
    #pragma unroll
    for (int c = 0; c < 2; ++c) {
      B8 x; x.v = vreg[c];
      U8 tt; tt.u = x.u;
      #pragma unroll
      for (int j = 0; j < 8; ++j) {
        int d = sc8 * 16 + c * 8 + j;
        sV[grp][d * 64 + (((srow >> 3) ^ j) << 3) + (srow & 7)] = tt.s[j];
      }
    }
  };

  if (grp < nt) { kload(grp); vload(grp); kstore(); vstore(); }

  constexpr float CEXP = 0.08838834764831845f * 1.44269504088896340f;
  u16* Pw = sP[wv];
  const u16* Kg = sK[grp];
  const u16* Vg = sV[grp];

  const int NS = (nt + 1) >> 1;
  for (int i = 0; i < NS; ++i) {
    __syncthreads();
    const int t  = 2 * i + grp;
    const int tn = t + 2;
    if (tn < nt) { kload(tn); vload(tn); }

    if (t < nt) {
      f32x4 S[4];
      #pragma unroll
      for (int jn = 0; jn < 4; ++jn) S[jn] = (f32x4){0.f, 0.f, 0.f, 0.f};
      #pragma unroll
      for (int c = 0; c < 4; ++c)
        #pragma unroll
        for (int jn = 0; jn < 4; ++jn) {
          B8 bb;
          bb.u = *(const uint4*)(&Kg[(jn * 16 + n) * 128 + (((c * 4 + quad) ^ n) << 3)]);
          S[jn] = __builtin_amdgcn_mfma_f32_16x16x32_bf16(qf[c], bb.v, S[jn], 0, 0, 0);
        }
      if (t * 64 + 64 > vl) {
        #pragma unroll
        for (int jn = 0; jn < 4; ++jn) {
          const bool msk = (t * 64 + jn * 16 + n) >= vl;
          #pragma unroll
          for (int r = 0; r < 4; ++r)
            S[jn][r] = msk ? -1e30f : S[jn][r];
        }
      }
      float al[4];
      #pragma unroll
      for (int r = 0; r < 4; ++r) {
        float mx = fmaxf(fmaxf(S[0][r], S[1][r]), fmaxf(S[2][r], S[3][r]));
        mx = rowmax16(mx);
        float mnew = fmaxf(mst[r], mx);
        float a = __builtin_exp2f((mst[r] - mnew) * CEXP);
        mst[r] = mnew;
        float ssum = 0.f;
        #pragma unroll
        for (int jn = 0; jn < 4; ++jn) {
          float p = __builtin_exp2f((S[jn][r] - mnew) * CEXP);
          S[jn][r] = p;
          ssum += p;
        }
        ssum = rowsum16(ssum);
        lst[r] = lst[r] * a + ssum;
        al[r] = a;
      }
      #pragma unroll
      for (int f = 0; f < 8; ++f) {
        O[f][0] *= al[0]; O[f][1] *= al[1]; O[f][2] *= al[2]; O[f][3] *= al[3];
      }
      #pragma unroll
      for (int jn = 0; jn < 4; ++jn)
        #pragma unroll
        for (int r = 0; r < 4; ++r) {
          int row = quad * 4 + r;
          __bf16 h = (__bf16)S[jn][r];
          Pw[row * 64 + (((jn * 2 + (n >> 3)) ^ (row & 7)) << 3) + (n & 7)]
              = __builtin_bit_cast(u16, h);
        }
      #pragma unroll
      for (int kc = 0; kc < 2; ++kc) {
        B8 ta;
        ta.u = *(const uint4*)(&Pw[n * 64 + (((kc * 4 + quad) ^ (n & 7)) << 3)]);
        bf16x8 af = ta.v;
        #pragma unroll
        for (int f = 0; f < 8; ++f) {
          int d = f * 16 + n;
          B8 bb;
          bb.u = *(const uint4*)(&Vg[d * 64 + (((kc * 4 + quad) ^ (n & 7)) << 3)]);
          O[f] = __builtin_amdgcn_mfma_f32_16x16x32_bf16(af, bb.v, O[f], 0, 0, 0);
        }
      }
    }
    __syncthreads();
    if (tn < nt) { kstore(); vstore(); }
  }

  if (grp == 1) {
    float* ob = ((qw < 4) ? (float*)sK : (float*)sV) + (qw & 3) * 2048 + lane * 32;
    #pragma unroll
    for (int f = 0; f < 8; ++f)
      #pragma unroll
      for (int r = 0; r < 4; ++r)
        ob[f * 4 + r] = O[f][r];
    float* sb = (float*)sP + qw * 512 + lane * 8;
    #pragma unroll
    for (int r = 0; r < 4; ++r) { sb[r] = mst[r]; sb[4 + r] = lst[r]; }
  }
  __syncthreads();
  if (grp == 0) {
    const float* ob = ((qw < 4) ? (const float*)sK : (const float*)sV) + (qw & 3) * 2048 + lane * 32;
    const float* sb = (const float*)sP + qw * 512 + lane * 8;
    #pragma unroll
    for (int r = 0; r < 4; ++r) {
      const float m1 = sb[r], l1 = sb[4 + r];
      const float m  = fmaxf(mst[r], m1);
      const float a0 = __builtin_exp2f((mst[r] - m) * CEXP);
      const float a1 = __builtin_exp2f((m1 - m) * CEXP);
      const float rl = 1.0f / (lst[r] * a0 + l1 * a1);
      const int qrow = qrow0 + quad * 4 + r;
      float* op = og + (size_t)(b * NQ + qrow) * ND + n;
      #pragma unroll
      for (int f = 0; f < 8; ++f)
        op[f * 16] = (O[f][r] * a0 + ob[f * 4 + r] * a1) * rl;
    }
  }
}

extern "C" void kernel_launch(void* const* d_in, const int* in_sizes, int n_in,
                              void* d_out, int out_size, void* d_ws, size_t ws_size,
                              hipStream_t stream) {
  const float* q  = (const float*)d_in[0];
  const float* k  = (const float*)d_in[1];
  const float* v  = (const float*)d_in[2];
  const int*  vl  = (const int*)d_in[3];
  float* out = (float*)d_out;

  const size_t need = (size_t)16 * 1024 * 1024;   // K + V bf16 tile images
  if (ws_size >= need) {
    u16* wk  = (u16*)d_ws;
    u16* wvv = wk + 4194304;
    hipLaunchKernelGGL(prepack, dim3(512), dim3(256), 0, stream, k, v, wk, wvv);
    hipLaunchKernelGGL(flash_fwd, dim3(256), dim3(512), 0, stream, q, vl, out, wk, wvv);
  } else {
    hipLaunchKernelGGL(flash_fwd_fb, dim3(256), dim3(1024), 0, stream, q, k, v, vl, out);
  }
}